// Round 7
// baseline (131.213 us; speedup 1.0000x reference)
//
#include <hip/hip_runtime.h>

#define BB 4
#define CC 16
#define TT 32
#define HWN 4096
#define NCH1 16      // k1 n-chunks of 256

// ws layout (float offsets)
#define WS_BQ   0                                  // [B][C*2=m][HWN]       524288
#define WS_QTP  (WS_BQ + BB*CC*2*HWN)              // [B][C][NCH1][192]     196608
#define WS_KSP  (WS_QTP + BB*CC*NCH1*192)          // [B][C][NCH1][8]       8192
#define WS_CST  (WS_KSP + BB*CC*NCH1*8)            // [B][T][32 m][2 mat][16 c] 131072

__device__ __forceinline__ float wsum64(float v){
#pragma unroll
  for (int m = 1; m < 64; m <<= 1) v += __shfl_xor(v, m, 64);
  return v;
}
__device__ __forceinline__ float wmax64(float v){
#pragma unroll
  for (int m = 1; m < 64; m <<= 1) v = fmaxf(v, __shfl_xor(v, m, 64));
  return v;
}
// sum over each quad (lanes 0-3, 4-7, ...) via DPP quad_perm — VALU pipe, no LDS
__device__ __forceinline__ float qsum4(float v){
  int a = __builtin_amdgcn_update_dpp(0, __float_as_int(v), 0xB1, 0xF, 0xF, true); // xor 1
  float r = v + __int_as_float(a);
  int b = __builtin_amdgcn_update_dpp(0, __float_as_int(r), 0x4E, 0xF, 0xF, true); // xor 2
  return r + __int_as_float(b);
}

// K1: grid (b, c, ch of 256 n) = 1024 blocks, 256 threads.
// wave w handles t in [8w, 8w+8); lane owns 4 n.
__global__ __launch_bounds__(256) void k1_stage(const float* __restrict__ x,
    const float* __restrict__ wqs, const float* __restrict__ wqt,
    float* __restrict__ ws)
{
  const int bx = blockIdx.x;
  const int ch = bx & 15;
  const int c  = (bx >> 4) & 15;
  const int b  = bx >> 8;
  const int tid  = threadIdx.x;
  const int wave = tid >> 6;
  const int lane = tid & 63;
  const int wave_u = __builtin_amdgcn_readfirstlane(wave);   // assert uniform -> s_loads

  __shared__ float4 sacc[4][64][6];      // 24 KB: per-wave qkv_s partials
  __shared__ float  qred[4*836];         // 13.4 KB: [wave]*836 + [quad]*52 + [k*8+tl]

  const int n0 = ch*256 + lane*4;
  const float* xrow = x + (((size_t)(b*CC + c))*TT + wave_u*8)*(size_t)HWN + n0;

  float4 wt4[6];
#pragma unroll
  for (int k = 0; k < 6; ++k)
    wt4[k] = *(const float4*)(wqt + k*HWN + n0);

  // wqs for this wave's 8 t — scalar (uniform) loads
  float wq[6][8];
#pragma unroll
  for (int k = 0; k < 6; ++k)
#pragma unroll
    for (int tl = 0; tl < 8; ++tl)
      wq[k][tl] = wqs[k*TT + wave_u*8 + tl];

  float acc[6][4];
  float qt[6][8];
#pragma unroll
  for (int k = 0; k < 6; ++k){
#pragma unroll
    for (int j = 0; j < 4; ++j) acc[k][j] = 0.f;
#pragma unroll
    for (int tl = 0; tl < 8; ++tl) qt[k][tl] = 0.f;
  }

  float4 xv = *(const float4*)(xrow);
#pragma unroll
  for (int tl = 0; tl < 8; ++tl){
    float4 nxt = xv;
    if (tl < 7) nxt = *(const float4*)(xrow + (size_t)(tl+1)*HWN);
#pragma unroll
    for (int k = 0; k < 6; ++k){
      const float w = wq[k][tl];
      acc[k][0] = fmaf(xv.x, w, acc[k][0]);
      acc[k][1] = fmaf(xv.y, w, acc[k][1]);
      acc[k][2] = fmaf(xv.z, w, acc[k][2]);
      acc[k][3] = fmaf(xv.w, w, acc[k][3]);
      float p = qt[k][tl];
      p = fmaf(xv.x, wt4[k].x, p);
      p = fmaf(xv.y, wt4[k].y, p);
      p = fmaf(xv.z, wt4[k].z, p);
      p = fmaf(xv.w, wt4[k].w, p);
      qt[k][tl] = p;
    }
    xv = nxt;
  }

  // qt reduction: quad-sum via DPP, then 16 quad-partials per wave to LDS
#pragma unroll
  for (int k = 0; k < 6; ++k)
#pragma unroll
    for (int tl = 0; tl < 8; ++tl)
      qt[k][tl] = qsum4(qt[k][tl]);
  if ((lane & 3) == 0){
    float* qp = &qred[wave*836 + (lane >> 2)*52];
#pragma unroll
    for (int k = 0; k < 6; ++k){
      *(float4*)(qp + k*8)     = make_float4(qt[k][0],qt[k][1],qt[k][2],qt[k][3]);
      *(float4*)(qp + k*8 + 4) = make_float4(qt[k][4],qt[k][5],qt[k][6],qt[k][7]);
    }
  }

#pragma unroll
  for (int k = 0; k < 6; ++k)
    sacc[wave][lane][k] = make_float4(acc[k][0], acc[k][1], acc[k][2], acc[k][3]);
  __syncthreads();

  const float eps = 1e-10f;

  // qt chunk partials -> global (192 threads, one per (k,t))
  if (tid < 192){
    const int k = tid >> 5, t = tid & 31, w = t >> 3, tl = t & 7;
    const float* qp = &qred[w*836 + k*8 + tl];
    float s = 0.f;
#pragma unroll
    for (int g = 0; g < 16; ++g) s += qp[g*52];
    ws[WS_QTP + ((size_t)((b*CC+c)*NCH1 + ch))*192 + tid] = s;
  }

  if (wave == 0){
    float4 s0 = sacc[0][lane][0], s1 = sacc[0][lane][1];
#pragma unroll
    for (int w = 1; w < 4; ++w){
      float4 a = sacc[w][lane][0], bq_ = sacc[w][lane][1];
      s0.x += a.x; s0.y += a.y; s0.z += a.z; s0.w += a.w;
      s1.x += bq_.x; s1.y += bq_.y; s1.z += bq_.z; s1.w += bq_.w;
    }
    float q0[4] = {s0.x, s0.y, s0.z, s0.w};
    float q1[4] = {s1.x, s1.y, s1.z, s1.w};
    float o0[4], o1[4];
#pragma unroll
    for (int j = 0; j < 4; ++j){
      float mm = fmaxf(q0[j], q1[j]);
      float e0 = __expf(q0[j]-mm), e1 = __expf(q1[j]-mm);
      float inv = 1.f/(e0+e1);
      o0[j] = sqrtf(e0*inv + eps);
      o1[j] = sqrtf(e1*inv + eps);
    }
    float* bqp = ws + WS_BQ + ((size_t)((b*CC+c)*2))*HWN + n0;
    *(float4*)(bqp)       = make_float4(o0[0],o0[1],o0[2],o0[3]);
    *(float4*)(bqp + HWN) = make_float4(o1[0],o1[1],o1[2],o1[3]);
  } else if (wave == 1){
    float4 ks0 = sacc[0][lane][2], ks1 = sacc[0][lane][3];
    float4 vs0 = sacc[0][lane][4], vs1 = sacc[0][lane][5];
#pragma unroll
    for (int w = 1; w < 4; ++w){
      float4 a = sacc[w][lane][2], bb = sacc[w][lane][3];
      float4 cc2 = sacc[w][lane][4], dd = sacc[w][lane][5];
      ks0.x += a.x; ks0.y += a.y; ks0.z += a.z; ks0.w += a.w;
      ks1.x += bb.x; ks1.y += bb.y; ks1.z += bb.z; ks1.w += bb.w;
      vs0.x += cc2.x; vs0.y += cc2.y; vs0.z += cc2.z; vs0.w += cc2.w;
      vs1.x += dd.x; vs1.y += dd.y; vs1.z += dd.z; vs1.w += dd.w;
    }
    float k0a[4] = {ks0.x,ks0.y,ks0.z,ks0.w};
    float k1a[4] = {ks1.x,ks1.y,ks1.z,ks1.w};
    float v0a[4] = {vs0.x,vs0.y,vs0.z,vs0.w};
    float v1a[4] = {vs1.x,vs1.y,vs1.z,vs1.w};
    float m0 = fmaxf(fmaxf(k0a[0],k0a[1]), fmaxf(k0a[2],k0a[3]));
    float m1 = fmaxf(fmaxf(k1a[0],k1a[1]), fmaxf(k1a[2],k1a[3]));
    m0 = wmax64(m0); m1 = wmax64(m1);
    float z0=0,z1=0,t00=0,t01=0,t10=0,t11=0;
#pragma unroll
    for (int j = 0; j < 4; ++j){
      float e0 = __expf(k0a[j]-m0);
      float e1 = __expf(k1a[j]-m1);
      z0 += e0; z1 += e1;
      float s0 = sqrtf(e0), s1 = sqrtf(e1);
      float v0 = sqrtf(v0a[j]), v1 = sqrtf(v1a[j]);
      t00 = fmaf(s0, v0, t00);
      t01 = fmaf(s1, v0, t01);
      t10 = fmaf(s0, v1, t10);
      t11 = fmaf(s1, v1, t11);
    }
    z0 = wsum64(z0); z1 = wsum64(z1);
    t00 = wsum64(t00); t01 = wsum64(t01); t10 = wsum64(t10); t11 = wsum64(t11);
    if (lane == 0){
      float* sp = ws + WS_KSP + ((size_t)((b*CC+c)*NCH1 + ch))*8;
      sp[0]=m0; sp[1]=m1; sp[2]=z0; sp[3]=z1;
      sp[4]=t00; sp[5]=t01; sp[6]=t10; sp[7]=t11;
    }
  }
}

// K23: one block per b (4 blocks, 256 threads): combine partials -> Aq, ctx
// (in LDS) -> materialize Cst[b][t][m][mat][c16] in ws.
__global__ __launch_bounds__(256) void k23_combine(const float* __restrict__ wos,
    const float* __restrict__ wot, float* __restrict__ ws)
{
  const int b = blockIdx.x;
  const int tid = threadIdx.x;
  __shared__ float qt_all[16][192];   // 12 KB
  __shared__ float aq[16][2][32];     // 4 KB
  __shared__ float ctxs[16][2][2];    // 256 B (includes scale^2: q-side and k-side)
  __shared__ float wo[2][512];        // 4 KB
  const float eps = 1e-10f;
  const float scale2 = 0.7071067811865476f;   // (KD^-0.25)^2 = 1/sqrt(2)

  for (int i = tid; i < 512; i += 256){
    wo[0][i] = wos[i];
    wo[1][i] = wot[i];
  }
  for (int i = tid; i < 3072; i += 256){
    const int c = i / 192, j = i - c*192;
    const float* qp = ws + WS_QTP + ((size_t)((b*CC+c)*NCH1))*192 + j;
    float s = 0.f;
#pragma unroll
    for (int ch = 0; ch < NCH1; ++ch) s += qp[ch*192];
    qt_all[c][j] = s;
  }
  __syncthreads();

  for (int i = tid; i < 512; i += 256){
    const int c = i >> 5, t = i & 31;
    float q0 = qt_all[c][t], q1 = qt_all[c][32+t];
    float mm = fmaxf(q0,q1);
    float e0 = __expf(q0-mm), e1 = __expf(q1-mm);
    float inv = 1.f/(e0+e1);
    aq[c][0][t] = sqrtf(e0*inv + eps);
    aq[c][1][t] = sqrtf(e1*inv + eps);
  }
  if (tid < 32){
    const int c = tid >> 1, d = tid & 1;
    const float* kt = &qt_all[c][(2+d)*32];
    float M = -1e30f;
    for (int t = 0; t < TT; ++t) M = fmaxf(M, kt[t]);
    float Z = 0.f;
    for (int t = 0; t < TT; ++t) Z += __expf(kt[t]-M);
    const float invZ = 1.f/Z;
    float St0 = 0.f, St1 = 0.f;
    for (int t = 0; t < TT; ++t){
      float r = sqrtf(__expf(kt[t]-M)*invZ + eps);
      St0 += r*sqrtf(qt_all[c][128+t]);
      St1 += r*sqrtf(qt_all[c][160+t]);
    }
    const float* kp = ws + WS_KSP + ((size_t)(b*CC+c))*NCH1*8;
    float M2 = -1e30f;
    for (int ch = 0; ch < NCH1; ++ch) M2 = fmaxf(M2, kp[ch*8+d]);
    float Z2 = 0.f, Sn0 = 0.f, Sn1 = 0.f;
    for (int ch = 0; ch < NCH1; ++ch){
      const float mc = kp[ch*8+d];
      Z2  += kp[ch*8+2+d]*__expf(mc-M2);
      const float hw = __expf((mc-M2)*0.5f);
      Sn0 += kp[ch*8+4+d]*hw;
      Sn1 += kp[ch*8+6+d]*hw;
    }
    const float invsZ = rsqrtf(Z2);
    ctxs[c][d][0] = scale2*St0*Sn0*invsZ;
    ctxs[c][d][1] = scale2*St1*Sn1*invsZ;
  }
  __syncthreads();

  // Cst: 32 t x 2 mat x 32 m items, 16 c values each
  for (int i = tid; i < 2048; i += 256){
    const int t = i >> 6, rem = i & 63, mat = rem >> 5, m = rem & 31;
    const int cp = m >> 1, d = m & 1;
    const float a  = aq[cp][d][t];
    const float a0 = a*ctxs[cp][d][0], a1 = a*ctxs[cp][d][1];
    float vals[16];
#pragma unroll
    for (int c = 0; c < CC; ++c)
      vals[c] = fmaf(wo[mat][c*32 + cp*2], a0, wo[mat][c*32 + cp*2 + 1]*a1);
    float* dst = ws + WS_CST + ((size_t)(b*TT+t))*1024 + m*32 + mat*16;
#pragma unroll
    for (int g = 0; g < 4; ++g)
      *(float4*)(dst + g*4) = make_float4(vals[g*4],vals[g*4+1],vals[g*4+2],vals[g*4+3]);
  }
}

#define FMA2(acc, s, v) { acc.x = fmaf(s, v.x, acc.x); acc.y = fmaf(s, v.y, acc.y); }

// K4: grid (b, t, c-half, n-chunk of 512) = 2048 blocks, 256 threads.
// Thread owns 2 n (float2), 8 c, both mats: 32 accs. 8 blocks/CU residency.
__global__ __launch_bounds__(256) void k4_out(const float* __restrict__ ws,
    float* __restrict__ out)
{
  const int bx = blockIdx.x;
  const int nch  = bx & 7;
  const int half = (bx >> 3) & 1;
  const int t    = (bx >> 4) & (TT-1);
  const int b    = bx >> 9;
  const int tid  = threadIdx.x;

  const int n0 = nch*512 + tid*2;
  const float* bqbase = ws + WS_BQ + ((size_t)(b*CC*2))*HWN + n0;
  const float* cst = ws + WS_CST + ((size_t)(b*TT+t))*1024 + half*8;

  float2 aS[8], aT[8];
#pragma unroll
  for (int c = 0; c < 8; ++c){
    aS[c] = make_float2(0.f,0.f);
    aT[c] = make_float2(0.f,0.f);
  }

#pragma unroll 8
  for (int m = 0; m < 32; ++m){
    const float2 bq = *(const float2*)(bqbase + (size_t)m*HWN);
    const float* cm = cst + m*32;
    const float4 cs0 = *(const float4*)(cm);
    const float4 cs1 = *(const float4*)(cm + 4);
    const float4 ct0 = *(const float4*)(cm + 16);
    const float4 ct1 = *(const float4*)(cm + 20);
    FMA2(aS[0], cs0.x, bq); FMA2(aS[1], cs0.y, bq);
    FMA2(aS[2], cs0.z, bq); FMA2(aS[3], cs0.w, bq);
    FMA2(aS[4], cs1.x, bq); FMA2(aS[5], cs1.y, bq);
    FMA2(aS[6], cs1.z, bq); FMA2(aS[7], cs1.w, bq);
    FMA2(aT[0], ct0.x, bq); FMA2(aT[1], ct0.y, bq);
    FMA2(aT[2], ct0.z, bq); FMA2(aT[3], ct0.w, bq);
    FMA2(aT[4], ct1.x, bq); FMA2(aT[5], ct1.y, bq);
    FMA2(aT[6], ct1.z, bq); FMA2(aT[7], ct1.w, bq);
  }

  float* outp = out + (((size_t)(b*CC + half*8))*TT + t)*HWN + n0;
#pragma unroll
  for (int c = 0; c < 8; ++c){
    float2 y;
    y.x = sqrtf(aS[c].x*aT[c].x);
    y.y = sqrtf(aS[c].y*aT[c].y);
    *(float2*)(outp + (size_t)c*TT*HWN) = y;
  }
}

extern "C" void kernel_launch(void* const* d_in, const int* in_sizes, int n_in,
                              void* d_out, int out_size, void* d_ws, size_t ws_size,
                              hipStream_t stream)
{
  const float* x   = (const float*)d_in[0];
  const float* wqs = (const float*)d_in[1];
  const float* wqt = (const float*)d_in[2];
  const float* wos = (const float*)d_in[3];
  const float* wot = (const float*)d_in[4];
  float* out = (float*)d_out;
  float* ws  = (float*)d_ws;

  hipLaunchKernelGGL(k1_stage, dim3(BB*CC*NCH1), dim3(256), 0, stream, x, wqs, wqt, ws);
  hipLaunchKernelGGL(k23_combine, dim3(BB), dim3(256), 0, stream, wos, wot, ws);
  hipLaunchKernelGGL(k4_out, dim3(BB*TT*2*8), dim3(256), 0, stream, ws, out);
}

// Round 8
// 127.311 us; speedup vs baseline: 1.0307x; 1.0307x over previous
//
#include <hip/hip_runtime.h>

#define BB 4
#define CC 16
#define TT 32
#define HWN 4096
#define NCH1 16      // k1 n-chunks of 256

// ws layout (float offsets)
#define WS_BQ   0                                  // [B][C*2=m][HWN]       524288
#define WS_QTP  (WS_BQ + BB*CC*2*HWN)              // [B][C][NCH1][192]     196608
#define WS_KSP  (WS_QTP + BB*CC*NCH1*192)          // [B][C][NCH1][8]       8192
#define WS_CST  (WS_KSP + BB*CC*NCH1*8)            // [B][T][32 m][2 mat][16 c] 131072

__device__ __forceinline__ float wsum64(float v){
#pragma unroll
  for (int m = 1; m < 64; m <<= 1) v += __shfl_xor(v, m, 64);
  return v;
}
__device__ __forceinline__ float wmax64(float v){
#pragma unroll
  for (int m = 1; m < 64; m <<= 1) v = fmaxf(v, __shfl_xor(v, m, 64));
  return v;
}
// sum over each quad (lanes 0-3, 4-7, ...) via DPP quad_perm — VALU pipe, no LDS
__device__ __forceinline__ float qsum4(float v){
  int a = __builtin_amdgcn_update_dpp(0, __float_as_int(v), 0xB1, 0xF, 0xF, true); // xor 1
  float r = v + __int_as_float(a);
  int b = __builtin_amdgcn_update_dpp(0, __float_as_int(r), 0x4E, 0xF, 0xF, true); // xor 2
  return r + __int_as_float(b);
}

// K1: grid (b, c, ch of 256 n) = 1024 blocks, 256 threads.
// wave w handles t in [8w, 8w+8); lane owns 4 n.
__global__ __launch_bounds__(256) void k1_stage(const float* __restrict__ x,
    const float* __restrict__ wqs, const float* __restrict__ wqt,
    float* __restrict__ ws)
{
  const int bx = blockIdx.x;
  const int ch = bx & 15;
  const int c  = (bx >> 4) & 15;
  const int b  = bx >> 8;
  const int tid  = threadIdx.x;
  const int wave = tid >> 6;
  const int lane = tid & 63;
  const int wave_u = __builtin_amdgcn_readfirstlane(wave);   // assert uniform -> s_loads

  __shared__ float4 sacc[4][64][6];      // 24 KB: per-wave qkv_s partials
  __shared__ float  qred[4*836];         // 13.4 KB: [wave]*836 + [quad]*52 + [k*8+tl]

  const int n0 = ch*256 + lane*4;
  const float* xrow = x + (((size_t)(b*CC + c))*TT + wave_u*8)*(size_t)HWN + n0;

  float4 wt4[6];
#pragma unroll
  for (int k = 0; k < 6; ++k)
    wt4[k] = *(const float4*)(wqt + k*HWN + n0);

  // wqs for this wave's 8 t — scalar (uniform) loads
  float wq[6][8];
#pragma unroll
  for (int k = 0; k < 6; ++k)
#pragma unroll
    for (int tl = 0; tl < 8; ++tl)
      wq[k][tl] = wqs[k*TT + wave_u*8 + tl];

  float acc[6][4];
  float qt[6][8];
#pragma unroll
  for (int k = 0; k < 6; ++k){
#pragma unroll
    for (int j = 0; j < 4; ++j) acc[k][j] = 0.f;
#pragma unroll
    for (int tl = 0; tl < 8; ++tl) qt[k][tl] = 0.f;
  }

  float4 xv = *(const float4*)(xrow);
#pragma unroll
  for (int tl = 0; tl < 8; ++tl){
    float4 nxt = xv;
    if (tl < 7) nxt = *(const float4*)(xrow + (size_t)(tl+1)*HWN);
#pragma unroll
    for (int k = 0; k < 6; ++k){
      const float w = wq[k][tl];
      acc[k][0] = fmaf(xv.x, w, acc[k][0]);
      acc[k][1] = fmaf(xv.y, w, acc[k][1]);
      acc[k][2] = fmaf(xv.z, w, acc[k][2]);
      acc[k][3] = fmaf(xv.w, w, acc[k][3]);
      float p = qt[k][tl];
      p = fmaf(xv.x, wt4[k].x, p);
      p = fmaf(xv.y, wt4[k].y, p);
      p = fmaf(xv.z, wt4[k].z, p);
      p = fmaf(xv.w, wt4[k].w, p);
      qt[k][tl] = p;
    }
    xv = nxt;
  }

  // qt reduction: quad-sum via DPP, then 16 quad-partials per wave to LDS
#pragma unroll
  for (int k = 0; k < 6; ++k)
#pragma unroll
    for (int tl = 0; tl < 8; ++tl)
      qt[k][tl] = qsum4(qt[k][tl]);
  if ((lane & 3) == 0){
    float* qp = &qred[wave*836 + (lane >> 2)*52];
#pragma unroll
    for (int k = 0; k < 6; ++k){
      *(float4*)(qp + k*8)     = make_float4(qt[k][0],qt[k][1],qt[k][2],qt[k][3]);
      *(float4*)(qp + k*8 + 4) = make_float4(qt[k][4],qt[k][5],qt[k][6],qt[k][7]);
    }
  }

#pragma unroll
  for (int k = 0; k < 6; ++k)
    sacc[wave][lane][k] = make_float4(acc[k][0], acc[k][1], acc[k][2], acc[k][3]);
  __syncthreads();

  const float eps = 1e-10f;

  // qt chunk partials -> global (192 threads, one per (k,t))
  if (tid < 192){
    const int k = tid >> 5, t = tid & 31, w = t >> 3, tl = t & 7;
    const float* qp = &qred[w*836 + k*8 + tl];
    float s = 0.f;
#pragma unroll
    for (int g = 0; g < 16; ++g) s += qp[g*52];
    ws[WS_QTP + ((size_t)((b*CC+c)*NCH1 + ch))*192 + tid] = s;
  }

  if (wave == 0){
    float4 s0 = sacc[0][lane][0], s1 = sacc[0][lane][1];
#pragma unroll
    for (int w = 1; w < 4; ++w){
      float4 a = sacc[w][lane][0], bq_ = sacc[w][lane][1];
      s0.x += a.x; s0.y += a.y; s0.z += a.z; s0.w += a.w;
      s1.x += bq_.x; s1.y += bq_.y; s1.z += bq_.z; s1.w += bq_.w;
    }
    float q0[4] = {s0.x, s0.y, s0.z, s0.w};
    float q1[4] = {s1.x, s1.y, s1.z, s1.w};
    float o0[4], o1[4];
#pragma unroll
    for (int j = 0; j < 4; ++j){
      float mm = fmaxf(q0[j], q1[j]);
      float e0 = __expf(q0[j]-mm), e1 = __expf(q1[j]-mm);
      float inv = 1.f/(e0+e1);
      o0[j] = sqrtf(e0*inv + eps);
      o1[j] = sqrtf(e1*inv + eps);
    }
    float* bqp = ws + WS_BQ + ((size_t)((b*CC+c)*2))*HWN + n0;
    *(float4*)(bqp)       = make_float4(o0[0],o0[1],o0[2],o0[3]);
    *(float4*)(bqp + HWN) = make_float4(o1[0],o1[1],o1[2],o1[3]);
  } else if (wave == 1){
    float4 ks0 = sacc[0][lane][2], ks1 = sacc[0][lane][3];
    float4 vs0 = sacc[0][lane][4], vs1 = sacc[0][lane][5];
#pragma unroll
    for (int w = 1; w < 4; ++w){
      float4 a = sacc[w][lane][2], bb = sacc[w][lane][3];
      float4 cc2 = sacc[w][lane][4], dd = sacc[w][lane][5];
      ks0.x += a.x; ks0.y += a.y; ks0.z += a.z; ks0.w += a.w;
      ks1.x += bb.x; ks1.y += bb.y; ks1.z += bb.z; ks1.w += bb.w;
      vs0.x += cc2.x; vs0.y += cc2.y; vs0.z += cc2.z; vs0.w += cc2.w;
      vs1.x += dd.x; vs1.y += dd.y; vs1.z += dd.z; vs1.w += dd.w;
    }
    float k0a[4] = {ks0.x,ks0.y,ks0.z,ks0.w};
    float k1a[4] = {ks1.x,ks1.y,ks1.z,ks1.w};
    float v0a[4] = {vs0.x,vs0.y,vs0.z,vs0.w};
    float v1a[4] = {vs1.x,vs1.y,vs1.z,vs1.w};
    float m0 = fmaxf(fmaxf(k0a[0],k0a[1]), fmaxf(k0a[2],k0a[3]));
    float m1 = fmaxf(fmaxf(k1a[0],k1a[1]), fmaxf(k1a[2],k1a[3]));
    m0 = wmax64(m0); m1 = wmax64(m1);
    float z0=0,z1=0,t00=0,t01=0,t10=0,t11=0;
#pragma unroll
    for (int j = 0; j < 4; ++j){
      float e0 = __expf(k0a[j]-m0);
      float e1 = __expf(k1a[j]-m1);
      z0 += e0; z1 += e1;
      float s0 = sqrtf(e0), s1 = sqrtf(e1);
      float v0 = sqrtf(v0a[j]), v1 = sqrtf(v1a[j]);
      t00 = fmaf(s0, v0, t00);
      t01 = fmaf(s1, v0, t01);
      t10 = fmaf(s0, v1, t10);
      t11 = fmaf(s1, v1, t11);
    }
    z0 = wsum64(z0); z1 = wsum64(z1);
    t00 = wsum64(t00); t01 = wsum64(t01); t10 = wsum64(t10); t11 = wsum64(t11);
    if (lane == 0){
      float* sp = ws + WS_KSP + ((size_t)((b*CC+c)*NCH1 + ch))*8;
      sp[0]=m0; sp[1]=m1; sp[2]=z0; sp[3]=z1;
      sp[4]=t00; sp[5]=t01; sp[6]=t10; sp[7]=t11;
    }
  }
}

// K23: one block per b (4 blocks, 256 threads): combine partials -> Aq, ctx
// (in LDS) -> materialize Cst[b][t][m][mat][c16] in ws.
__global__ __launch_bounds__(256) void k23_combine(const float* __restrict__ wos,
    const float* __restrict__ wot, float* __restrict__ ws)
{
  const int b = blockIdx.x;
  const int tid = threadIdx.x;
  __shared__ float qt_all[16][192];   // 12 KB
  __shared__ float aq[16][2][32];     // 4 KB
  __shared__ float ctxs[16][2][2];    // 256 B (includes scale^2: q-side and k-side)
  __shared__ float wo[2][512];        // 4 KB
  const float eps = 1e-10f;
  const float scale2 = 0.7071067811865476f;   // (KD^-0.25)^2 = 1/sqrt(2)

  for (int i = tid; i < 512; i += 256){
    wo[0][i] = wos[i];
    wo[1][i] = wot[i];
  }
  for (int i = tid; i < 3072; i += 256){
    const int c = i / 192, j = i - c*192;
    const float* qp = ws + WS_QTP + ((size_t)((b*CC+c)*NCH1))*192 + j;
    float s = 0.f;
#pragma unroll
    for (int ch = 0; ch < NCH1; ++ch) s += qp[ch*192];
    qt_all[c][j] = s;
  }
  __syncthreads();

  for (int i = tid; i < 512; i += 256){
    const int c = i >> 5, t = i & 31;
    float q0 = qt_all[c][t], q1 = qt_all[c][32+t];
    float mm = fmaxf(q0,q1);
    float e0 = __expf(q0-mm), e1 = __expf(q1-mm);
    float inv = 1.f/(e0+e1);
    aq[c][0][t] = sqrtf(e0*inv + eps);
    aq[c][1][t] = sqrtf(e1*inv + eps);
  }
  if (tid < 32){
    const int c = tid >> 1, d = tid & 1;
    const float* kt = &qt_all[c][(2+d)*32];
    float M = -1e30f;
    for (int t = 0; t < TT; ++t) M = fmaxf(M, kt[t]);
    float Z = 0.f;
    for (int t = 0; t < TT; ++t) Z += __expf(kt[t]-M);
    const float invZ = 1.f/Z;
    float St0 = 0.f, St1 = 0.f;
    for (int t = 0; t < TT; ++t){
      float r = sqrtf(__expf(kt[t]-M)*invZ + eps);
      St0 += r*sqrtf(qt_all[c][128+t]);
      St1 += r*sqrtf(qt_all[c][160+t]);
    }
    const float* kp = ws + WS_KSP + ((size_t)(b*CC+c))*NCH1*8;
    float M2 = -1e30f;
    for (int ch = 0; ch < NCH1; ++ch) M2 = fmaxf(M2, kp[ch*8+d]);
    float Z2 = 0.f, Sn0 = 0.f, Sn1 = 0.f;
    for (int ch = 0; ch < NCH1; ++ch){
      const float mc = kp[ch*8+d];
      Z2  += kp[ch*8+2+d]*__expf(mc-M2);
      const float hw = __expf((mc-M2)*0.5f);
      Sn0 += kp[ch*8+4+d]*hw;
      Sn1 += kp[ch*8+6+d]*hw;
    }
    const float invsZ = rsqrtf(Z2);
    ctxs[c][d][0] = scale2*St0*Sn0*invsZ;
    ctxs[c][d][1] = scale2*St1*Sn1*invsZ;
  }
  __syncthreads();

  // Cst: 32 t x 2 mat x 32 m items, 16 c values each
  for (int i = tid; i < 2048; i += 256){
    const int t = i >> 6, rem = i & 63, mat = rem >> 5, m = rem & 31;
    const int cp = m >> 1, d = m & 1;
    const float a  = aq[cp][d][t];
    const float a0 = a*ctxs[cp][d][0], a1 = a*ctxs[cp][d][1];
    float vals[16];
#pragma unroll
    for (int c = 0; c < CC; ++c)
      vals[c] = fmaf(wo[mat][c*32 + cp*2], a0, wo[mat][c*32 + cp*2 + 1]*a1);
    float* dst = ws + WS_CST + ((size_t)(b*TT+t))*1024 + m*32 + mat*16;
#pragma unroll
    for (int g = 0; g < 4; ++g)
      *(float4*)(dst + g*4) = make_float4(vals[g*4],vals[g*4+1],vals[g*4+2],vals[g*4+3]);
  }
}

#define FMA4(acc, s, v) { acc.x = fmaf(s, v.x, acc.x); acc.y = fmaf(s, v.y, acc.y); \
                          acc.z = fmaf(s, v.z, acc.z); acc.w = fmaf(s, v.w, acc.w); }

// K4: grid (b, t, c-half, n-chunk of 1024) = 1024 blocks, 256 threads.
// Thread owns 4 n (float4), 8 c, both mats: 64 accs. m-loop: 1 bq float4 load
// + 4 uniform (scalar) float4 cs/ct loads + 64 FMA.  [round-5 proven config]
__global__ __launch_bounds__(256) void k4_out(const float* __restrict__ ws,
    float* __restrict__ out)
{
  const int bx = blockIdx.x;
  const int nch  = bx & 3;
  const int half = (bx >> 2) & 1;
  const int t    = (bx >> 3) & (TT-1);
  const int b    = bx >> 8;
  const int tid  = threadIdx.x;

  const int n0 = nch*1024 + tid*4;
  const float* bqbase = ws + WS_BQ + ((size_t)(b*CC*2))*HWN + n0;
  const float* cst = ws + WS_CST + ((size_t)(b*TT+t))*1024 + half*8;

  float4 aS[8], aT[8];
#pragma unroll
  for (int c = 0; c < 8; ++c){
    aS[c] = make_float4(0,0,0,0);
    aT[c] = make_float4(0,0,0,0);
  }

#pragma unroll 4
  for (int m = 0; m < 32; ++m){
    const float4 bq = *(const float4*)(bqbase + (size_t)m*HWN);
    const float* cm = cst + m*32;
    const float4 cs0 = *(const float4*)(cm);
    const float4 cs1 = *(const float4*)(cm + 4);
    const float4 ct0 = *(const float4*)(cm + 16);
    const float4 ct1 = *(const float4*)(cm + 20);
    FMA4(aS[0], cs0.x, bq); FMA4(aS[1], cs0.y, bq);
    FMA4(aS[2], cs0.z, bq); FMA4(aS[3], cs0.w, bq);
    FMA4(aS[4], cs1.x, bq); FMA4(aS[5], cs1.y, bq);
    FMA4(aS[6], cs1.z, bq); FMA4(aS[7], cs1.w, bq);
    FMA4(aT[0], ct0.x, bq); FMA4(aT[1], ct0.y, bq);
    FMA4(aT[2], ct0.z, bq); FMA4(aT[3], ct0.w, bq);
    FMA4(aT[4], ct1.x, bq); FMA4(aT[5], ct1.y, bq);
    FMA4(aT[6], ct1.z, bq); FMA4(aT[7], ct1.w, bq);
  }

  float* outp = out + (((size_t)(b*CC + half*8))*TT + t)*HWN + n0;
#pragma unroll
  for (int c = 0; c < 8; ++c){
    float4 y;
    y.x = sqrtf(aS[c].x*aT[c].x);
    y.y = sqrtf(aS[c].y*aT[c].y);
    y.z = sqrtf(aS[c].z*aT[c].z);
    y.w = sqrtf(aS[c].w*aT[c].w);
    *(float4*)(outp + (size_t)c*TT*HWN) = y;
  }
}

extern "C" void kernel_launch(void* const* d_in, const int* in_sizes, int n_in,
                              void* d_out, int out_size, void* d_ws, size_t ws_size,
                              hipStream_t stream)
{
  const float* x   = (const float*)d_in[0];
  const float* wqs = (const float*)d_in[1];
  const float* wqt = (const float*)d_in[2];
  const float* wos = (const float*)d_in[3];
  const float* wot = (const float*)d_in[4];
  float* out = (float*)d_out;
  float* ws  = (float*)d_ws;

  hipLaunchKernelGGL(k1_stage, dim3(BB*CC*NCH1), dim3(256), 0, stream, x, wqs, wqt, ws);
  hipLaunchKernelGGL(k23_combine, dim3(BB), dim3(256), 0, stream, wos, wot, ws);
  hipLaunchKernelGGL(k4_out, dim3(BB*TT*8), dim3(256), 0, stream, ws, out);
}

// Round 9
// 121.397 us; speedup vs baseline: 1.0809x; 1.0487x over previous
//
#include <hip/hip_runtime.h>

#define BB 4
#define CC 16
#define TT 32
#define HWN 4096
#define NCH1 16      // k1 n-chunks of 256

// ws layout (float offsets)
#define WS_BQ   0                                  // [B][C*2=m][HWN]       524288
#define WS_QTP  (WS_BQ + BB*CC*2*HWN)              // [B][C][NCH1][192]     196608
#define WS_KSP  (WS_QTP + BB*CC*NCH1*192)          // [B][C][NCH1][8]       8192
#define WS_AQ   (WS_KSP + BB*CC*NCH1*8)            // [B][C][2][TT]         4096
#define WS_CTX  (WS_AQ + BB*CC*2*TT)               // [B][C][2][2]          256
#define WS_CST  (WS_CTX + BB*CC*2*2)               // [B][T][32 m][2 mat][16 c] 131072

__device__ __forceinline__ float wsum64(float v){
#pragma unroll
  for (int m = 1; m < 64; m <<= 1) v += __shfl_xor(v, m, 64);
  return v;
}
__device__ __forceinline__ float wmax64(float v){
#pragma unroll
  for (int m = 1; m < 64; m <<= 1) v = fmaxf(v, __shfl_xor(v, m, 64));
  return v;
}
// sum over each quad (lanes 0-3, 4-7, ...) via DPP quad_perm — VALU pipe, no LDS
__device__ __forceinline__ float qsum4(float v){
  int a = __builtin_amdgcn_update_dpp(0, __float_as_int(v), 0xB1, 0xF, 0xF, true); // xor 1
  float r = v + __int_as_float(a);
  int b = __builtin_amdgcn_update_dpp(0, __float_as_int(r), 0x4E, 0xF, 0xF, true); // xor 2
  return r + __int_as_float(b);
}

// K1: grid (b, c, ch of 256 n) = 1024 blocks, 256 threads.
// wave w handles t in [8w, 8w+8); lane owns 4 n.
__global__ __launch_bounds__(256) void k1_stage(const float* __restrict__ x,
    const float* __restrict__ wqs, const float* __restrict__ wqt,
    float* __restrict__ ws)
{
  const int bx = blockIdx.x;
  const int ch = bx & 15;
  const int c  = (bx >> 4) & 15;
  const int b  = bx >> 8;
  const int tid  = threadIdx.x;
  const int wave = tid >> 6;
  const int lane = tid & 63;
  const int wave_u = __builtin_amdgcn_readfirstlane(wave);   // assert uniform -> s_loads

  __shared__ float4 sacc[4][64][6];      // 24 KB: per-wave qkv_s partials
  __shared__ float  qred[4*836];         // 13.4 KB: [wave]*836 + [quad]*52 + [k*8+tl]

  const int n0 = ch*256 + lane*4;
  const float* xrow = x + (((size_t)(b*CC + c))*TT + wave_u*8)*(size_t)HWN + n0;

  float4 wt4[6];
#pragma unroll
  for (int k = 0; k < 6; ++k)
    wt4[k] = *(const float4*)(wqt + k*HWN + n0);

  // wqs for this wave's 8 t — scalar (uniform) loads
  float wq[6][8];
#pragma unroll
  for (int k = 0; k < 6; ++k)
#pragma unroll
    for (int tl = 0; tl < 8; ++tl)
      wq[k][tl] = wqs[k*TT + wave_u*8 + tl];

  float acc[6][4];
  float qt[6][8];
#pragma unroll
  for (int k = 0; k < 6; ++k){
#pragma unroll
    for (int j = 0; j < 4; ++j) acc[k][j] = 0.f;
#pragma unroll
    for (int tl = 0; tl < 8; ++tl) qt[k][tl] = 0.f;
  }

  float4 xv = *(const float4*)(xrow);
#pragma unroll
  for (int tl = 0; tl < 8; ++tl){
    float4 nxt = xv;
    if (tl < 7) nxt = *(const float4*)(xrow + (size_t)(tl+1)*HWN);
#pragma unroll
    for (int k = 0; k < 6; ++k){
      const float w = wq[k][tl];
      acc[k][0] = fmaf(xv.x, w, acc[k][0]);
      acc[k][1] = fmaf(xv.y, w, acc[k][1]);
      acc[k][2] = fmaf(xv.z, w, acc[k][2]);
      acc[k][3] = fmaf(xv.w, w, acc[k][3]);
      float p = qt[k][tl];
      p = fmaf(xv.x, wt4[k].x, p);
      p = fmaf(xv.y, wt4[k].y, p);
      p = fmaf(xv.z, wt4[k].z, p);
      p = fmaf(xv.w, wt4[k].w, p);
      qt[k][tl] = p;
    }
    xv = nxt;
  }

  // qt reduction: quad-sum via DPP, then 16 quad-partials per wave to LDS
#pragma unroll
  for (int k = 0; k < 6; ++k)
#pragma unroll
    for (int tl = 0; tl < 8; ++tl)
      qt[k][tl] = qsum4(qt[k][tl]);
  if ((lane & 3) == 0){
    float* qp = &qred[wave*836 + (lane >> 2)*52];
#pragma unroll
    for (int k = 0; k < 6; ++k){
      *(float4*)(qp + k*8)     = make_float4(qt[k][0],qt[k][1],qt[k][2],qt[k][3]);
      *(float4*)(qp + k*8 + 4) = make_float4(qt[k][4],qt[k][5],qt[k][6],qt[k][7]);
    }
  }

#pragma unroll
  for (int k = 0; k < 6; ++k)
    sacc[wave][lane][k] = make_float4(acc[k][0], acc[k][1], acc[k][2], acc[k][3]);
  __syncthreads();

  const float eps = 1e-10f;

  // qt chunk partials -> global (192 threads, one per (k,t))
  if (tid < 192){
    const int k = tid >> 5, t = tid & 31, w = t >> 3, tl = t & 7;
    const float* qp = &qred[w*836 + k*8 + tl];
    float s = 0.f;
#pragma unroll
    for (int g = 0; g < 16; ++g) s += qp[g*52];
    ws[WS_QTP + ((size_t)((b*CC+c)*NCH1 + ch))*192 + tid] = s;
  }

  if (wave == 0){
    float4 s0 = sacc[0][lane][0], s1 = sacc[0][lane][1];
#pragma unroll
    for (int w = 1; w < 4; ++w){
      float4 a = sacc[w][lane][0], bq_ = sacc[w][lane][1];
      s0.x += a.x; s0.y += a.y; s0.z += a.z; s0.w += a.w;
      s1.x += bq_.x; s1.y += bq_.y; s1.z += bq_.z; s1.w += bq_.w;
    }
    float q0[4] = {s0.x, s0.y, s0.z, s0.w};
    float q1[4] = {s1.x, s1.y, s1.z, s1.w};
    float o0[4], o1[4];
#pragma unroll
    for (int j = 0; j < 4; ++j){
      float mm = fmaxf(q0[j], q1[j]);
      float e0 = __expf(q0[j]-mm), e1 = __expf(q1[j]-mm);
      float inv = 1.f/(e0+e1);
      o0[j] = sqrtf(e0*inv + eps);
      o1[j] = sqrtf(e1*inv + eps);
    }
    float* bqp = ws + WS_BQ + ((size_t)((b*CC+c)*2))*HWN + n0;
    *(float4*)(bqp)       = make_float4(o0[0],o0[1],o0[2],o0[3]);
    *(float4*)(bqp + HWN) = make_float4(o1[0],o1[1],o1[2],o1[3]);
  } else if (wave == 1){
    float4 ks0 = sacc[0][lane][2], ks1 = sacc[0][lane][3];
    float4 vs0 = sacc[0][lane][4], vs1 = sacc[0][lane][5];
#pragma unroll
    for (int w = 1; w < 4; ++w){
      float4 a = sacc[w][lane][2], bb = sacc[w][lane][3];
      float4 cc2 = sacc[w][lane][4], dd = sacc[w][lane][5];
      ks0.x += a.x; ks0.y += a.y; ks0.z += a.z; ks0.w += a.w;
      ks1.x += bb.x; ks1.y += bb.y; ks1.z += bb.z; ks1.w += bb.w;
      vs0.x += cc2.x; vs0.y += cc2.y; vs0.z += cc2.z; vs0.w += cc2.w;
      vs1.x += dd.x; vs1.y += dd.y; vs1.z += dd.z; vs1.w += dd.w;
    }
    float k0a[4] = {ks0.x,ks0.y,ks0.z,ks0.w};
    float k1a[4] = {ks1.x,ks1.y,ks1.z,ks1.w};
    float v0a[4] = {vs0.x,vs0.y,vs0.z,vs0.w};
    float v1a[4] = {vs1.x,vs1.y,vs1.z,vs1.w};
    float m0 = fmaxf(fmaxf(k0a[0],k0a[1]), fmaxf(k0a[2],k0a[3]));
    float m1 = fmaxf(fmaxf(k1a[0],k1a[1]), fmaxf(k1a[2],k1a[3]));
    m0 = wmax64(m0); m1 = wmax64(m1);
    float z0=0,z1=0,t00=0,t01=0,t10=0,t11=0;
#pragma unroll
    for (int j = 0; j < 4; ++j){
      float e0 = __expf(k0a[j]-m0);
      float e1 = __expf(k1a[j]-m1);
      z0 += e0; z1 += e1;
      float s0 = sqrtf(e0), s1 = sqrtf(e1);
      float v0 = sqrtf(v0a[j]), v1 = sqrtf(v1a[j]);
      t00 = fmaf(s0, v0, t00);
      t01 = fmaf(s1, v0, t01);
      t10 = fmaf(s0, v1, t10);
      t11 = fmaf(s1, v1, t11);
    }
    z0 = wsum64(z0); z1 = wsum64(z1);
    t00 = wsum64(t00); t01 = wsum64(t01); t10 = wsum64(t10); t11 = wsum64(t11);
    if (lane == 0){
      float* sp = ws + WS_KSP + ((size_t)((b*CC+c)*NCH1 + ch))*8;
      sp[0]=m0; sp[1]=m1; sp[2]=z0; sp[3]=z1;
      sp[4]=t00; sp[5]=t01; sp[6]=t10; sp[7]=t11;
    }
  }
}

// K2: grid 64 (one per (b,c)) x 256 threads: combine 16 chunk partials ->
// Aq, ctx (scale^2 folded into ctx).
__global__ __launch_bounds__(256) void k2_combine(float* __restrict__ ws)
{
  const int bc_ = blockIdx.x;
  const int tid = threadIdx.x;
  __shared__ float qt[192];
  const float eps = 1e-10f;
  const float scale2 = 0.7071067811865476f;   // (KD^-0.25)^2 = 1/sqrt(2)

  if (tid < 192){
    const float* qp = ws + WS_QTP + ((size_t)bc_*NCH1)*192 + tid;
    float s = 0.f;
#pragma unroll
    for (int ch = 0; ch < NCH1; ++ch)
      s += qp[ch*192];
    qt[tid] = s;
  }
  __syncthreads();

  if (tid < TT){
    const int t = tid;
    float q0 = qt[t], q1 = qt[32+t];
    float mm = fmaxf(q0,q1);
    float e0 = __expf(q0-mm), e1 = __expf(q1-mm);
    float inv = 1.f/(e0+e1);
    ws[WS_AQ + (bc_*2+0)*TT + t] = sqrtf(e0*inv + eps);
    ws[WS_AQ + (bc_*2+1)*TT + t] = sqrtf(e1*inv + eps);
  }
  if (tid < 2){
    const int d = tid;
    const float* kt = &qt[(2+d)*32];
    float M = -1e30f;
    for (int t = 0; t < TT; ++t) M = fmaxf(M, kt[t]);
    float Z = 0.f;
    for (int t = 0; t < TT; ++t) Z += __expf(kt[t]-M);
    const float invZ = 1.f/Z;
    float St0 = 0.f, St1 = 0.f;
    for (int t = 0; t < TT; ++t){
      float r = sqrtf(__expf(kt[t]-M)*invZ + eps);
      St0 += r*sqrtf(qt[128+t]);
      St1 += r*sqrtf(qt[160+t]);
    }
    const float* kp = ws + WS_KSP + (size_t)bc_*NCH1*8;
    float M2 = -1e30f;
    for (int ch = 0; ch < NCH1; ++ch) M2 = fmaxf(M2, kp[ch*8+d]);
    float Z2 = 0.f, Sn0 = 0.f, Sn1 = 0.f;
    for (int ch = 0; ch < NCH1; ++ch){
      const float mc = kp[ch*8+d];
      Z2  += kp[ch*8+2+d]*__expf(mc-M2);
      const float hw = __expf((mc-M2)*0.5f);
      Sn0 += kp[ch*8+4+d]*hw;
      Sn1 += kp[ch*8+6+d]*hw;
    }
    const float invsZ = rsqrtf(Z2);
    ws[WS_CTX + (bc_*2+d)*2+0] = scale2*St0*Sn0*invsZ;
    ws[WS_CTX + (bc_*2+d)*2+1] = scale2*St1*Sn1*invsZ;
  }
}

// K3: materialize Cst[b][t][m][mat][c16]. grid 128 x 64 (tid = mat*32+m).
__global__ __launch_bounds__(64) void k3_cs(const float* __restrict__ wos,
    const float* __restrict__ wot, float* __restrict__ ws)
{
  const int bx = blockIdx.x;
  const int b = bx >> 5, t = bx & 31;
  const int tid = threadIdx.x;
  const int mat = tid >> 5, m = tid & 31;
  const int cp = m >> 1, d = m & 1;

  const float aq = ws[WS_AQ + ((size_t)((b*CC+cp)*2+d))*TT + t];
  const float c0 = ws[WS_CTX + ((b*CC+cp)*2+d)*2 + 0];   // scale^2 already folded
  const float c1 = ws[WS_CTX + ((b*CC+cp)*2+d)*2 + 1];
  const float a0 = aq*c0, a1 = aq*c1;
  const float* wmat = mat ? wot : wos;
  float vals[16];
#pragma unroll
  for (int c = 0; c < CC; ++c)
    vals[c] = fmaf(wmat[c*32 + cp*2], a0, wmat[c*32 + cp*2 + 1]*a1);
  float* dst = ws + WS_CST + ((size_t)(b*TT+t))*1024 + m*32 + mat*16;
#pragma unroll
  for (int g = 0; g < 4; ++g)
    *(float4*)(dst + g*4) = make_float4(vals[g*4],vals[g*4+1],vals[g*4+2],vals[g*4+3]);
}

#define FMA4(acc, s, v) { acc.x = fmaf(s, v.x, acc.x); acc.y = fmaf(s, v.y, acc.y); \
                          acc.z = fmaf(s, v.z, acc.z); acc.w = fmaf(s, v.w, acc.w); }

// K4: grid (b, t, c-half, n-chunk of 1024) = 1024 blocks, 256 threads.
// Thread owns 4 n (float4), 8 c, both mats: 64 accs. m-loop: 1 bq float4 load
// + 4 uniform (scalar) float4 cs/ct loads + 64 FMA.  [round-5 proven config]
__global__ __launch_bounds__(256) void k4_out(const float* __restrict__ ws,
    float* __restrict__ out)
{
  const int bx = blockIdx.x;
  const int nch  = bx & 3;
  const int half = (bx >> 2) & 1;
  const int t    = (bx >> 3) & (TT-1);
  const int b    = bx >> 8;
  const int tid  = threadIdx.x;

  const int n0 = nch*1024 + tid*4;
  const float* bqbase = ws + WS_BQ + ((size_t)(b*CC*2))*HWN + n0;
  const float* cst = ws + WS_CST + ((size_t)(b*TT+t))*1024 + half*8;

  float4 aS[8], aT[8];
#pragma unroll
  for (int c = 0; c < 8; ++c){
    aS[c] = make_float4(0,0,0,0);
    aT[c] = make_float4(0,0,0,0);
  }

#pragma unroll 4
  for (int m = 0; m < 32; ++m){
    const float4 bq = *(const float4*)(bqbase + (size_t)m*HWN);
    const float* cm = cst + m*32;
    const float4 cs0 = *(const float4*)(cm);
    const float4 cs1 = *(const float4*)(cm + 4);
    const float4 ct0 = *(const float4*)(cm + 16);
    const float4 ct1 = *(const float4*)(cm + 20);
    FMA4(aS[0], cs0.x, bq); FMA4(aS[1], cs0.y, bq);
    FMA4(aS[2], cs0.z, bq); FMA4(aS[3], cs0.w, bq);
    FMA4(aS[4], cs1.x, bq); FMA4(aS[5], cs1.y, bq);
    FMA4(aS[6], cs1.z, bq); FMA4(aS[7], cs1.w, bq);
    FMA4(aT[0], ct0.x, bq); FMA4(aT[1], ct0.y, bq);
    FMA4(aT[2], ct0.z, bq); FMA4(aT[3], ct0.w, bq);
    FMA4(aT[4], ct1.x, bq); FMA4(aT[5], ct1.y, bq);
    FMA4(aT[6], ct1.z, bq); FMA4(aT[7], ct1.w, bq);
  }

  float* outp = out + (((size_t)(b*CC + half*8))*TT + t)*HWN + n0;
#pragma unroll
  for (int c = 0; c < 8; ++c){
    float4 y;
    y.x = sqrtf(aS[c].x*aT[c].x);
    y.y = sqrtf(aS[c].y*aT[c].y);
    y.z = sqrtf(aS[c].z*aT[c].z);
    y.w = sqrtf(aS[c].w*aT[c].w);
    *(float4*)(outp + (size_t)c*TT*HWN) = y;
  }
}

extern "C" void kernel_launch(void* const* d_in, const int* in_sizes, int n_in,
                              void* d_out, int out_size, void* d_ws, size_t ws_size,
                              hipStream_t stream)
{
  const float* x   = (const float*)d_in[0];
  const float* wqs = (const float*)d_in[1];
  const float* wqt = (const float*)d_in[2];
  const float* wos = (const float*)d_in[3];
  const float* wot = (const float*)d_in[4];
  float* out = (float*)d_out;
  float* ws  = (float*)d_ws;

  hipLaunchKernelGGL(k1_stage, dim3(BB*CC*NCH1), dim3(256), 0, stream, x, wqs, wqt, ws);
  hipLaunchKernelGGL(k2_combine, dim3(BB*CC), dim3(256), 0, stream, ws);
  hipLaunchKernelGGL(k3_cs, dim3(BB*TT), dim3(64), 0, stream, wos, wot, ws);
  hipLaunchKernelGGL(k4_out, dim3(BB*TT*8), dim3(256), 0, stream, ws, out);
}

// Round 10
// 118.488 us; speedup vs baseline: 1.1074x; 1.0246x over previous
//
#include <hip/hip_runtime.h>

#define BB 4
#define CC 16
#define TT 32
#define HWN 4096
#define NCH1 16      // k1 n-chunks of 256

// ws layout (float offsets)
#define WS_BQ   0                                  // [B][C*2=m][HWN]       524288
#define WS_QTP  (WS_BQ + BB*CC*2*HWN)              // [B][C][NCH1][192]     196608
#define WS_KSP  (WS_QTP + BB*CC*NCH1*192)          // [B][C][NCH1][8]       8192
#define WS_CST  (WS_KSP + BB*CC*NCH1*8)            // [B][T][32 m][2 mat][16 c] 131072

__device__ __forceinline__ float wsum64(float v){
#pragma unroll
  for (int m = 1; m < 64; m <<= 1) v += __shfl_xor(v, m, 64);
  return v;
}
__device__ __forceinline__ float wmax64(float v){
#pragma unroll
  for (int m = 1; m < 64; m <<= 1) v = fmaxf(v, __shfl_xor(v, m, 64));
  return v;
}
// sum over each quad (lanes 0-3, 4-7, ...) via DPP quad_perm — VALU pipe, no LDS
__device__ __forceinline__ float qsum4(float v){
  int a = __builtin_amdgcn_update_dpp(0, __float_as_int(v), 0xB1, 0xF, 0xF, true); // xor 1
  float r = v + __int_as_float(a);
  int b = __builtin_amdgcn_update_dpp(0, __float_as_int(r), 0x4E, 0xF, 0xF, true); // xor 2
  return r + __int_as_float(b);
}

// K1: grid (b, c, ch of 256 n) = 1024 blocks, 256 threads.
// wave w handles t in [8w, 8w+8); lane owns 4 n.
__global__ __launch_bounds__(256) void k1_stage(const float* __restrict__ x,
    const float* __restrict__ wqs, const float* __restrict__ wqt,
    float* __restrict__ ws)
{
  const int bx = blockIdx.x;
  const int ch = bx & 15;
  const int c  = (bx >> 4) & 15;
  const int b  = bx >> 8;
  const int tid  = threadIdx.x;
  const int wave = tid >> 6;
  const int lane = tid & 63;
  const int wave_u = __builtin_amdgcn_readfirstlane(wave);   // assert uniform -> s_loads

  __shared__ float4 sacc[4][64][6];      // 24 KB: per-wave qkv_s partials
  __shared__ float  qred[4*836];         // 13.4 KB: [wave]*836 + [quad]*52 + [k*8+tl]

  const int n0 = ch*256 + lane*4;
  const float* xrow = x + (((size_t)(b*CC + c))*TT + wave_u*8)*(size_t)HWN + n0;

  float4 wt4[6];
#pragma unroll
  for (int k = 0; k < 6; ++k)
    wt4[k] = *(const float4*)(wqt + k*HWN + n0);

  // wqs for this wave's 8 t — scalar (uniform) loads
  float wq[6][8];
#pragma unroll
  for (int k = 0; k < 6; ++k)
#pragma unroll
    for (int tl = 0; tl < 8; ++tl)
      wq[k][tl] = wqs[k*TT + wave_u*8 + tl];

  float acc[6][4];
  float qt[6][8];
#pragma unroll
  for (int k = 0; k < 6; ++k){
#pragma unroll
    for (int j = 0; j < 4; ++j) acc[k][j] = 0.f;
#pragma unroll
    for (int tl = 0; tl < 8; ++tl) qt[k][tl] = 0.f;
  }

  float4 xv = *(const float4*)(xrow);
#pragma unroll
  for (int tl = 0; tl < 8; ++tl){
    float4 nxt = xv;
    if (tl < 7) nxt = *(const float4*)(xrow + (size_t)(tl+1)*HWN);
#pragma unroll
    for (int k = 0; k < 6; ++k){
      const float w = wq[k][tl];
      acc[k][0] = fmaf(xv.x, w, acc[k][0]);
      acc[k][1] = fmaf(xv.y, w, acc[k][1]);
      acc[k][2] = fmaf(xv.z, w, acc[k][2]);
      acc[k][3] = fmaf(xv.w, w, acc[k][3]);
      float p = qt[k][tl];
      p = fmaf(xv.x, wt4[k].x, p);
      p = fmaf(xv.y, wt4[k].y, p);
      p = fmaf(xv.z, wt4[k].z, p);
      p = fmaf(xv.w, wt4[k].w, p);
      qt[k][tl] = p;
    }
    xv = nxt;
  }

  // qt reduction: quad-sum via DPP, then 16 quad-partials per wave to LDS
#pragma unroll
  for (int k = 0; k < 6; ++k)
#pragma unroll
    for (int tl = 0; tl < 8; ++tl)
      qt[k][tl] = qsum4(qt[k][tl]);
  if ((lane & 3) == 0){
    float* qp = &qred[wave*836 + (lane >> 2)*52];
#pragma unroll
    for (int k = 0; k < 6; ++k){
      *(float4*)(qp + k*8)     = make_float4(qt[k][0],qt[k][1],qt[k][2],qt[k][3]);
      *(float4*)(qp + k*8 + 4) = make_float4(qt[k][4],qt[k][5],qt[k][6],qt[k][7]);
    }
  }

#pragma unroll
  for (int k = 0; k < 6; ++k)
    sacc[wave][lane][k] = make_float4(acc[k][0], acc[k][1], acc[k][2], acc[k][3]);
  __syncthreads();

  const float eps = 1e-10f;

  // qt chunk partials -> global (192 threads, one per (k,t))
  if (tid < 192){
    const int k = tid >> 5, t = tid & 31, w = t >> 3, tl = t & 7;
    const float* qp = &qred[w*836 + k*8 + tl];
    float s = 0.f;
#pragma unroll
    for (int g = 0; g < 16; ++g) s += qp[g*52];
    ws[WS_QTP + ((size_t)((b*CC+c)*NCH1 + ch))*192 + tid] = s;
  }

  if (wave == 0){
    float4 s0 = sacc[0][lane][0], s1 = sacc[0][lane][1];
#pragma unroll
    for (int w = 1; w < 4; ++w){
      float4 a = sacc[w][lane][0], bq_ = sacc[w][lane][1];
      s0.x += a.x; s0.y += a.y; s0.z += a.z; s0.w += a.w;
      s1.x += bq_.x; s1.y += bq_.y; s1.z += bq_.z; s1.w += bq_.w;
    }
    float q0[4] = {s0.x, s0.y, s0.z, s0.w};
    float q1[4] = {s1.x, s1.y, s1.z, s1.w};
    float o0[4], o1[4];
#pragma unroll
    for (int j = 0; j < 4; ++j){
      float mm = fmaxf(q0[j], q1[j]);
      float e0 = __expf(q0[j]-mm), e1 = __expf(q1[j]-mm);
      float inv = 1.f/(e0+e1);
      o0[j] = sqrtf(e0*inv + eps);
      o1[j] = sqrtf(e1*inv + eps);
    }
    float* bqp = ws + WS_BQ + ((size_t)((b*CC+c)*2))*HWN + n0;
    *(float4*)(bqp)       = make_float4(o0[0],o0[1],o0[2],o0[3]);
    *(float4*)(bqp + HWN) = make_float4(o1[0],o1[1],o1[2],o1[3]);
  } else if (wave == 1){
    float4 ks0 = sacc[0][lane][2], ks1 = sacc[0][lane][3];
    float4 vs0 = sacc[0][lane][4], vs1 = sacc[0][lane][5];
#pragma unroll
    for (int w = 1; w < 4; ++w){
      float4 a = sacc[w][lane][2], bb = sacc[w][lane][3];
      float4 cc2 = sacc[w][lane][4], dd = sacc[w][lane][5];
      ks0.x += a.x; ks0.y += a.y; ks0.z += a.z; ks0.w += a.w;
      ks1.x += bb.x; ks1.y += bb.y; ks1.z += bb.z; ks1.w += bb.w;
      vs0.x += cc2.x; vs0.y += cc2.y; vs0.z += cc2.z; vs0.w += cc2.w;
      vs1.x += dd.x; vs1.y += dd.y; vs1.z += dd.z; vs1.w += dd.w;
    }
    float k0a[4] = {ks0.x,ks0.y,ks0.z,ks0.w};
    float k1a[4] = {ks1.x,ks1.y,ks1.z,ks1.w};
    float v0a[4] = {vs0.x,vs0.y,vs0.z,vs0.w};
    float v1a[4] = {vs1.x,vs1.y,vs1.z,vs1.w};
    float m0 = fmaxf(fmaxf(k0a[0],k0a[1]), fmaxf(k0a[2],k0a[3]));
    float m1 = fmaxf(fmaxf(k1a[0],k1a[1]), fmaxf(k1a[2],k1a[3]));
    m0 = wmax64(m0); m1 = wmax64(m1);
    float z0=0,z1=0,t00=0,t01=0,t10=0,t11=0;
#pragma unroll
    for (int j = 0; j < 4; ++j){
      float e0 = __expf(k0a[j]-m0);
      float e1 = __expf(k1a[j]-m1);
      z0 += e0; z1 += e1;
      float s0 = sqrtf(e0), s1 = sqrtf(e1);
      float v0 = sqrtf(v0a[j]), v1 = sqrtf(v1a[j]);
      t00 = fmaf(s0, v0, t00);
      t01 = fmaf(s1, v0, t01);
      t10 = fmaf(s0, v1, t10);
      t11 = fmaf(s1, v1, t11);
    }
    z0 = wsum64(z0); z1 = wsum64(z1);
    t00 = wsum64(t00); t01 = wsum64(t01); t10 = wsum64(t10); t11 = wsum64(t11);
    if (lane == 0){
      float* sp = ws + WS_KSP + ((size_t)((b*CC+c)*NCH1 + ch))*8;
      sp[0]=m0; sp[1]=m1; sp[2]=z0; sp[3]=z1;
      sp[4]=t00; sp[5]=t01; sp[6]=t10; sp[7]=t11;
    }
  }
}

// K23b: grid 64 (one per (b,cp)) x 256 threads. Combine 16 chunk partials ->
// Aq, ctx in LDS -> write this cp's complete Cst slice [t][m=cp*2+d][mat][c].
// Parallel shape everywhere (no 4-block serial trap like R6-R8's k23).
__global__ __launch_bounds__(256) void k23b(const float* __restrict__ wos,
    const float* __restrict__ wot, float* __restrict__ ws)
{
  const int bc_ = blockIdx.x;          // b*CC + cp
  const int b  = bc_ >> 4;
  const int cp = bc_ & 15;
  const int tid = threadIdx.x;
  __shared__ float qt[192];
  __shared__ float aq[2][32];
  __shared__ float ctx[2][2];          // [d][e], scale^2 folded
  __shared__ float wc[2][2][16];       // [d][mat][c] = w0*ctx[d][0] + w1*ctx[d][1]
  const float eps = 1e-10f;
  const float scale2 = 0.7071067811865476f;   // (KD^-0.25)^2 = 1/sqrt(2)

  if (tid < 192){
    const float* qp = ws + WS_QTP + ((size_t)bc_*NCH1)*192 + tid;
    float s = 0.f;
#pragma unroll
    for (int ch = 0; ch < NCH1; ++ch)
      s += qp[ch*192];
    qt[tid] = s;
  }
  __syncthreads();

  if (tid < TT){
    const int t = tid;
    float q0 = qt[t], q1 = qt[32+t];
    float mm = fmaxf(q0,q1);
    float e0 = __expf(q0-mm), e1 = __expf(q1-mm);
    float inv = 1.f/(e0+e1);
    aq[0][t] = sqrtf(e0*inv + eps);
    aq[1][t] = sqrtf(e1*inv + eps);
  }
  if (tid >= 32 && tid < 34){
    const int d = tid - 32;
    const float* kt = &qt[(2+d)*32];
    float M = -1e30f;
    for (int t = 0; t < TT; ++t) M = fmaxf(M, kt[t]);
    float Z = 0.f;
    for (int t = 0; t < TT; ++t) Z += __expf(kt[t]-M);
    const float invZ = 1.f/Z;
    float St0 = 0.f, St1 = 0.f;
    for (int t = 0; t < TT; ++t){
      float r = sqrtf(__expf(kt[t]-M)*invZ + eps);
      St0 += r*sqrtf(qt[128+t]);
      St1 += r*sqrtf(qt[160+t]);
    }
    const float* kp = ws + WS_KSP + (size_t)bc_*NCH1*8;
    float M2 = -1e30f;
    for (int ch = 0; ch < NCH1; ++ch) M2 = fmaxf(M2, kp[ch*8+d]);
    float Z2 = 0.f, Sn0 = 0.f, Sn1 = 0.f;
    for (int ch = 0; ch < NCH1; ++ch){
      const float mc = kp[ch*8+d];
      Z2  += kp[ch*8+2+d]*__expf(mc-M2);
      const float hw = __expf((mc-M2)*0.5f);
      Sn0 += kp[ch*8+4+d]*hw;
      Sn1 += kp[ch*8+6+d]*hw;
    }
    const float invsZ = rsqrtf(Z2);
    ctx[d][0] = scale2*St0*Sn0*invsZ;
    ctx[d][1] = scale2*St1*Sn1*invsZ;
  }
  __syncthreads();

  // wc[d][mat][c]
  if (tid < 64){
    const int d = tid >> 5, mat = (tid >> 4) & 1, c = tid & 15;
    const float* wmat = mat ? wot : wos;
    wc[d][mat][c] = fmaf(wmat[c*32 + cp*2], ctx[d][0], wmat[c*32 + cp*2 + 1]*ctx[d][1]);
  }
  __syncthreads();

  // write Cst: 2048 floats, 8 per thread (two float4)
  const int t   = tid >> 3;
  const int sub = tid & 7;
  const int d   = sub >> 2;
  const int mat = (sub >> 1) & 1;
  const int c8  = (sub & 1) * 8;
  const float a = aq[d][t];
  float4 v0, v1;
  v0.x = a*wc[d][mat][c8+0]; v0.y = a*wc[d][mat][c8+1];
  v0.z = a*wc[d][mat][c8+2]; v0.w = a*wc[d][mat][c8+3];
  v1.x = a*wc[d][mat][c8+4]; v1.y = a*wc[d][mat][c8+5];
  v1.z = a*wc[d][mat][c8+6]; v1.w = a*wc[d][mat][c8+7];
  float* dst = ws + WS_CST + ((size_t)(b*TT+t))*1024 + (cp*2+d)*32 + mat*16 + c8;
  *(float4*)(dst)     = v0;
  *(float4*)(dst + 4) = v1;
}

#define FMA4(acc, s, v) { acc.x = fmaf(s, v.x, acc.x); acc.y = fmaf(s, v.y, acc.y); \
                          acc.z = fmaf(s, v.z, acc.z); acc.w = fmaf(s, v.w, acc.w); }

// K4: grid (b, t, c-half, n-chunk of 1024) = 1024 blocks, 256 threads.
// Thread owns 4 n (float4), 8 c, both mats: 64 accs. m-loop: 1 bq float4 load
// + 4 uniform (scalar) float4 cs/ct loads + 64 FMA.  [round-5 proven config]
__global__ __launch_bounds__(256) void k4_out(const float* __restrict__ ws,
    float* __restrict__ out)
{
  const int bx = blockIdx.x;
  const int nch  = bx & 3;
  const int half = (bx >> 2) & 1;
  const int t    = (bx >> 3) & (TT-1);
  const int b    = bx >> 8;
  const int tid  = threadIdx.x;

  const int n0 = nch*1024 + tid*4;
  const float* bqbase = ws + WS_BQ + ((size_t)(b*CC*2))*HWN + n0;
  const float* cst = ws + WS_CST + ((size_t)(b*TT+t))*1024 + half*8;

  float4 aS[8], aT[8];
#pragma unroll
  for (int c = 0; c < 8; ++c){
    aS[c] = make_float4(0,0,0,0);
    aT[c] = make_float4(0,0,0,0);
  }

#pragma unroll 4
  for (int m = 0; m < 32; ++m){
    const float4 bq = *(const float4*)(bqbase + (size_t)m*HWN);
    const float* cm = cst + m*32;
    const float4 cs0 = *(const float4*)(cm);
    const float4 cs1 = *(const float4*)(cm + 4);
    const float4 ct0 = *(const float4*)(cm + 16);
    const float4 ct1 = *(const float4*)(cm + 20);
    FMA4(aS[0], cs0.x, bq); FMA4(aS[1], cs0.y, bq);
    FMA4(aS[2], cs0.z, bq); FMA4(aS[3], cs0.w, bq);
    FMA4(aS[4], cs1.x, bq); FMA4(aS[5], cs1.y, bq);
    FMA4(aS[6], cs1.z, bq); FMA4(aS[7], cs1.w, bq);
    FMA4(aT[0], ct0.x, bq); FMA4(aT[1], ct0.y, bq);
    FMA4(aT[2], ct0.z, bq); FMA4(aT[3], ct0.w, bq);
    FMA4(aT[4], ct1.x, bq); FMA4(aT[5], ct1.y, bq);
    FMA4(aT[6], ct1.z, bq); FMA4(aT[7], ct1.w, bq);
  }

  float* outp = out + (((size_t)(b*CC + half*8))*TT + t)*HWN + n0;
#pragma unroll
  for (int c = 0; c < 8; ++c){
    float4 y;
    y.x = sqrtf(aS[c].x*aT[c].x);
    y.y = sqrtf(aS[c].y*aT[c].y);
    y.z = sqrtf(aS[c].z*aT[c].z);
    y.w = sqrtf(aS[c].w*aT[c].w);
    *(float4*)(outp + (size_t)c*TT*HWN) = y;
  }
}

extern "C" void kernel_launch(void* const* d_in, const int* in_sizes, int n_in,
                              void* d_out, int out_size, void* d_ws, size_t ws_size,
                              hipStream_t stream)
{
  const float* x   = (const float*)d_in[0];
  const float* wqs = (const float*)d_in[1];
  const float* wqt = (const float*)d_in[2];
  const float* wos = (const float*)d_in[3];
  const float* wot = (const float*)d_in[4];
  float* out = (float*)d_out;
  float* ws  = (float*)d_ws;

  hipLaunchKernelGGL(k1_stage, dim3(BB*CC*NCH1), dim3(256), 0, stream, x, wqs, wqt, ws);
  hipLaunchKernelGGL(k23b, dim3(BB*CC), dim3(256), 0, stream, wos, wot, ws);
  hipLaunchKernelGGL(k4_out, dim3(BB*TT*8), dim3(256), 0, stream, ws, out);
}